// Round 5
// baseline (166.178 us; speedup 1.0000x reference)
//
#include <hip/hip_runtime.h>

typedef _Float16 f16;
typedef __attribute__((ext_vector_type(8))) _Float16 f16x8;
typedef __attribute__((ext_vector_type(4))) float    f32x4;

#define NP 13          // Wn0..6 -> p=0..6, Ws0..5 -> p=7..12; result = outputs[7]
#define THREADS 512    // 8 waves/block, 1 block/CU (LDS ~105 KB) -> 8 waves/CU
#define NBLOCKS 256
#define TILES 2        // 2048 waves * 2 tiles * 64 rows = 262144

// Verified (R2-R4 passes) conventions for mfma_f32_16x16x32_f16, D[m][n]=sum_k A[m][k]B[n][k]:
//   A/B frag: lane(q=lane>>4, l15=lane&15) holds [m|n = l15][k = q*8+j], j=0..7
//   C/D:      col(n)=l15, row(m)=q*4+reg
// A = W (m = output feature), B = h (n = batch row). C has batch on lanes -> C feeds the
// next layer's B-frag with NO cross-lane movement, using the k-slot permutation
//   slot(q,kb,jh,jl) <-> feature F = kb*32 + jh*16 + q*4 + jl
// baked into the LDS weight layout (k is dummy; permutation cancels in the MFMA sum).
//
// __launch_bounds__(512, 1): R2-R4 all compiled to a 128-VGPR cap with arg=2 or no arg
// (CUDA minBlocks semantics: 2 blocks -> 4 waves/EU -> 128). LDS already pins occupancy
// at 1 block/CU = 2 waves/EU, so arg=1 lifts the cap to 256 at zero occupancy cost.
__global__ __launch_bounds__(THREADS, 1)
void nn_fused(const float* __restrict__ x,
              const float* __restrict__ Wn, const float* __restrict__ bn,
              const float* __restrict__ Ws, const float* __restrict__ bs,
              float* __restrict__ out)
{
    __shared__ f16   w_lds[NP * 4096];   // [p][f=64][slot=64], 16B chunks XOR-swizzled by f&7
    __shared__ float b_lds[NP * 64];     // f32 biases, r-strided: [p][ (f&3)*16 + (f>>2) ]

    const int tid = threadIdx.x;

    // ---- stage weights: dest chunk ch=(q<<1|kb) holds slots with jh=0..1, jl=0..3 ----
    for (int c = tid; c < NP * 512; c += THREADS) {
        const int p = c >> 9, f = (c >> 3) & 63, ch = c & 7;
        const int qq = ch >> 1, kb = ch & 1;
        const float* src = (p < 7 ? Wn + p * 4096 : Ws + (p - 7) * 4096) + f * 64;
        f32x4 a, b;
        __builtin_memcpy(&a, src + kb * 32 + qq * 4, 16);       // jh=0: features kb*32+qq*4+jl
        __builtin_memcpy(&b, src + kb * 32 + 16 + qq * 4, 16);  // jh=1: +16
        f16x8 v;
        v[0]=(f16)a.x; v[1]=(f16)a.y; v[2]=(f16)a.z; v[3]=(f16)a.w;
        v[4]=(f16)b.x; v[5]=(f16)b.y; v[6]=(f16)b.z; v[7]=(f16)b.w;
        __builtin_memcpy(&w_lds[p * 4096 + f * 64 + ((ch ^ (f & 7)) << 3)], &v, 16);
    }
    // biases: r-strided layout so the 4 per-ft reads stay separate b32 broadcasts
    // (R3/R4's same-address ds_read_b64 correlated with 0.9-1.5M bank conflicts; b32
    // same-address broadcast is verified free).
    for (int i = tid; i < NP * 64; i += THREADS) {
        const int p = i >> 6, f = i & 63;
        const float v = (p < 7) ? bn[p * 64 + f] : bs[(p - 7) * 64 + f];
        b_lds[p * 64 + (f & 3) * 16 + (f >> 2)] = v;
    }
    __syncthreads();   // only barrier in the kernel

    const int lane = tid & 63;
    const int wid  = tid >> 6;
    const int l15  = lane & 15;
    const int q    = lane >> 4;
    const int gw   = blockIdx.x * (THREADS / 64) + wid;   // 0..2047

    auto wfrag = [&](int p, int ft, int kb) -> f16x8 {     // A-operand: W rows, un-swizzle
        const int f = ft * 16 + l15;
        const int chs = ((q << 1) | kb) ^ (f & 7);
        f16x8 v;
        __builtin_memcpy(&v, &w_lds[p * 4096 + f * 64 + (chs << 3)], 16);
        return v;
    };
    auto bias4 = [&](int p, int ft) -> f32x4 {   // bias for features ft*16 + q*4 + r
        f32x4 b;
#pragma unroll
        for (int r = 0; r < 4; ++r) b[r] = b_lds[p * 64 + r * 16 + (ft * 4 + q)];
        return b;
    };

    // ---- prefetch BOTH tiles' x as B-frags (hides tile-1's HBM latency under tile-0) ----
    f16x8 xf[TILES][4][2];
#pragma unroll
    for (int t = 0; t < TILES; ++t)
#pragma unroll
    for (int nb = 0; nb < 4; ++nb) {
        const float* xr = x + (((long)gw + (long)t * (NBLOCKS * THREADS / 64)) * 64
                               + nb * 16 + l15) * 64;
#pragma unroll
        for (int kb = 0; kb < 2; ++kb) {
            f32x4 a, b;
            __builtin_memcpy(&a, xr + kb * 32 + q * 4, 16);
            __builtin_memcpy(&b, xr + kb * 32 + 16 + q * 4, 16);
            f16x8 v;
            v[0]=(f16)a.x; v[1]=(f16)a.y; v[2]=(f16)a.z; v[3]=(f16)a.w;
            v[4]=(f16)b.x; v[5]=(f16)b.y; v[6]=(f16)b.z; v[7]=(f16)b.w;
            xf[t][nb][kb] = v;
        }
    }

    for (int t = 0; t < TILES; ++t) {
        const long row0 = ((long)gw + (long)t * (NBLOCKS * THREADS / 64)) * 64;

        f16x8 hp[4][2], hp2[4][2];
#pragma unroll
        for (int nb = 0; nb < 4; ++nb)
#pragma unroll
        for (int kb = 0; kb < 2; ++kb) hp2[nb][kb] = xf[t][nb][kb];

        // ---- layer 1: hp = relu(x Wn0^T + bn0) ----
#pragma unroll
        for (int ft = 0; ft < 4; ++ft) {
            const f16x8 w0 = wfrag(0, ft, 0), w1 = wfrag(0, ft, 1);
            const f32x4 bv = bias4(0, ft);
#pragma unroll
            for (int nb = 0; nb < 4; ++nb) {
                f32x4 an = bv;
                an = __builtin_amdgcn_mfma_f32_16x16x32_f16(w0, hp2[nb][0], an, 0, 0, 0);
                an = __builtin_amdgcn_mfma_f32_16x16x32_f16(w1, hp2[nb][1], an, 0, 0, 0);
#pragma unroll
                for (int r = 0; r < 4; ++r)
                    hp[nb][ft >> 1][(ft & 1) * 4 + r] = (f16)fmaxf(an[r], 0.f);
            }
        }

        // ---- layers 2..6 (runtime loop keeps lifetimes per-layer) ----
#pragma unroll 1
        for (int l = 2; l <= 6; ++l) {
            const int pn = l - 1, ps = l + 5;   // 7 + (l-2)
            f16x8 hnew[4][2];
#pragma unroll
            for (int ft = 0; ft < 4; ++ft) {
                const f16x8 wn0 = wfrag(pn, ft, 0), wn1 = wfrag(pn, ft, 1);
                const f16x8 ws0 = wfrag(ps, ft, 0), ws1 = wfrag(ps, ft, 1);
                const f32x4 bnv = bias4(pn, ft),  bsv = bias4(ps, ft);
#pragma unroll
                for (int nb = 0; nb < 4; ++nb) {
                    f32x4 an = bnv, as = bsv;
                    an = __builtin_amdgcn_mfma_f32_16x16x32_f16(wn0, hp[nb][0],  an, 0, 0, 0);
                    an = __builtin_amdgcn_mfma_f32_16x16x32_f16(wn1, hp[nb][1],  an, 0, 0, 0);
                    as = __builtin_amdgcn_mfma_f32_16x16x32_f16(ws0, hp2[nb][0], as, 0, 0, 0);
                    as = __builtin_amdgcn_mfma_f32_16x16x32_f16(ws1, hp2[nb][1], as, 0, 0, 0);
#pragma unroll
                    for (int r = 0; r < 4; ++r)
                        hnew[nb][ft >> 1][(ft & 1) * 4 + r] =
                            (f16)(fmaxf(an[r], 0.f) + fmaxf(as[r], 0.f));
                }
            }
#pragma unroll
            for (int nb = 0; nb < 4; ++nb)
#pragma unroll
            for (int kb = 0; kb < 2; ++kb) {
                hp2[nb][kb] = hp[nb][kb];
                hp[nb][kb]  = hnew[nb][kb];
            }
        }

        // ---- layer 7: out = relu(h6 Wn6^T + bn6) + relu(h5 Ws5^T + bs5), fp32 store ----
#pragma unroll
        for (int ft = 0; ft < 4; ++ft) {
            const f16x8 wn0 = wfrag(6, ft, 0),  wn1 = wfrag(6, ft, 1);
            const f16x8 ws0 = wfrag(12, ft, 0), ws1 = wfrag(12, ft, 1);
            const f32x4 bnv = bias4(6, ft),     bsv = bias4(12, ft);
#pragma unroll
            for (int nb = 0; nb < 4; ++nb) {
                f32x4 an = bnv, as = bsv;
                an = __builtin_amdgcn_mfma_f32_16x16x32_f16(wn0, hp[nb][0],  an, 0, 0, 0);
                an = __builtin_amdgcn_mfma_f32_16x16x32_f16(wn1, hp[nb][1],  an, 0, 0, 0);
                as = __builtin_amdgcn_mfma_f32_16x16x32_f16(ws0, hp2[nb][0], as, 0, 0, 0);
                as = __builtin_amdgcn_mfma_f32_16x16x32_f16(ws1, hp2[nb][1], as, 0, 0, 0);
                f32x4 v;
#pragma unroll
                for (int r = 0; r < 4; ++r) v[r] = fmaxf(an[r], 0.f) + fmaxf(as[r], 0.f);
                float* orow = out + (row0 + nb * 16 + l15) * 64;
                __builtin_memcpy(orow + ft * 16 + q * 4, &v, 16);
            }
        }
    }
}

extern "C" void kernel_launch(void* const* d_in, const int* in_sizes, int n_in,
                              void* d_out, int out_size, void* d_ws, size_t ws_size,
                              hipStream_t stream) {
    (void)in_sizes; (void)n_in; (void)d_ws; (void)ws_size; (void)out_size;
    const float* x  = (const float*)d_in[0];
    const float* Wn = (const float*)d_in[1];
    const float* bn = (const float*)d_in[2];
    const float* Ws = (const float*)d_in[3];
    const float* bs = (const float*)d_in[4];
    nn_fused<<<dim3(NBLOCKS), dim3(THREADS), 0, stream>>>(x, Wn, bn, Ws, bs, (float*)d_out);
}

// Round 6
// 143.092 us; speedup vs baseline: 1.1613x; 1.1613x over previous
//
#include <hip/hip_runtime.h>

typedef _Float16 f16;
typedef __attribute__((ext_vector_type(8))) _Float16 f16x8;
typedef __attribute__((ext_vector_type(4))) float    f32x4;

#define NP 13          // Wn0..6 -> p=0..6, Ws0..5 -> p=7..12; result = outputs[7]
#define THREADS 512    // 8 waves/block, 1 block/CU (LDS ~105 KB) -> 8 waves/CU
#define NBLOCKS 256
#define TILES 4        // 2048 waves * 4 tiles * 32 rows = 262144

// Verified (R2-R5 passes) conventions for mfma_f32_16x16x32_f16, D[m][n]=sum_k A[m][k]B[n][k]:
//   A/B frag: lane(q=lane>>4, l15=lane&15) holds [m|n = l15][k = q*8+j], j=0..7
//   C/D:      col(n)=l15, row(m)=q*4+reg
// A = W (m = output feature), B = h (n = batch row). C has batch on lanes -> C feeds the
// next layer's B-frag with NO cross-lane movement, using the k-slot permutation
//   chunk(kb,q) holds features F = kb*32 + jh*16 + q*4 + jl  (element j = jh*4+jl)
// baked into the LDS weight layout (k is dummy; permutation cancels in the MFMA sum).
// Chunk packing index kb*4+q (R2's exact zero-conflict pattern, vs R3-R5's (q<<1)|kb).
//
// Empirical law (R3/R4/R5): this toolchain pins VGPR_Count at 128 regardless of
// __launch_bounds__; anything over spills to scratch (+30-50 MB HBM traffic).
// => 32-row tiles: peak register demand ~92, comfortably under the cap.
__global__ __launch_bounds__(THREADS)
void nn_fused(const float* __restrict__ x,
              const float* __restrict__ Wn, const float* __restrict__ bn,
              const float* __restrict__ Ws, const float* __restrict__ bs,
              float* __restrict__ out)
{
    __shared__ f16   w_lds[NP * 4096];   // [p][f=64][slot=64], 16B chunks XOR-swizzled by f&7
    __shared__ float b_lds[NP * 64];     // f32 biases, r-strided: [p][(f&3)*16 + (f>>2)]

    const int tid = threadIdx.x;

    // ---- stage weights: dest chunk ch = kb*4+qq holds features kb*32 + jh*16 + qq*4 + jl ----
    for (int c = tid; c < NP * 512; c += THREADS) {
        const int p = c >> 9, f = (c >> 3) & 63, ch = c & 7;
        const int kb = ch >> 2, qq = ch & 3;
        const float* src = (p < 7 ? Wn + p * 4096 : Ws + (p - 7) * 4096) + f * 64;
        f32x4 a, b;
        __builtin_memcpy(&a, src + kb * 32 + qq * 4, 16);       // jh=0
        __builtin_memcpy(&b, src + kb * 32 + 16 + qq * 4, 16);  // jh=1
        f16x8 v;
        v[0]=(f16)a.x; v[1]=(f16)a.y; v[2]=(f16)a.z; v[3]=(f16)a.w;
        v[4]=(f16)b.x; v[5]=(f16)b.y; v[6]=(f16)b.z; v[7]=(f16)b.w;
        __builtin_memcpy(&w_lds[p * 4096 + f * 64 + ((ch ^ (f & 7)) << 3)], &v, 16);
    }
    // biases r-strided so per-ft reads are 4 separate b32 16-lane broadcasts (conflict-free)
    for (int i = tid; i < NP * 64; i += THREADS) {
        const int p = i >> 6, f = i & 63;
        const float v = (p < 7) ? bn[p * 64 + f] : bs[(p - 7) * 64 + f];
        b_lds[p * 64 + (f & 3) * 16 + (f >> 2)] = v;
    }
    __syncthreads();   // only barrier in the kernel

    const int lane = tid & 63;
    const int wid  = tid >> 6;
    const int l15  = lane & 15;
    const int q    = lane >> 4;
    const int gw   = blockIdx.x * (THREADS / 64) + wid;   // 0..2047

    auto wfrag = [&](int p, int ft, int kb) -> f16x8 {     // A-operand: W rows, un-swizzle
        const int f = ft * 16 + l15;
        const int chs = (kb * 4 + q) ^ (f & 7);            // R2-packing
        f16x8 v;
        __builtin_memcpy(&v, &w_lds[p * 4096 + f * 64 + (chs << 3)], 16);
        return v;
    };
    auto bias4 = [&](int p, int ft) -> f32x4 {   // bias for features ft*16 + q*4 + r
        f32x4 b;
#pragma unroll
        for (int r = 0; r < 4; ++r) b[r] = b_lds[p * 64 + r * 16 + (ft * 4 + q)];
        return b;
    };

#pragma unroll 1
    for (int t = 0; t < TILES; ++t) {
        const long row0 = ((long)gw + (long)t * (NBLOCKS * THREADS / 64)) * 32;

        f16x8 hp[2][2], hp2[2][2];   // h_{l-1}, h_{l-2} B-frags for 32 batch rows

        // ---- x -> B-frags (into hp2; x is layer-2's skip input) ----
#pragma unroll
        for (int nb = 0; nb < 2; ++nb) {
            const float* xr = x + (row0 + nb * 16 + l15) * 64;
#pragma unroll
            for (int kb = 0; kb < 2; ++kb) {
                f32x4 a, b;
                __builtin_memcpy(&a, xr + kb * 32 + q * 4, 16);
                __builtin_memcpy(&b, xr + kb * 32 + 16 + q * 4, 16);
                f16x8 v;
                v[0]=(f16)a.x; v[1]=(f16)a.y; v[2]=(f16)a.z; v[3]=(f16)a.w;
                v[4]=(f16)b.x; v[5]=(f16)b.y; v[6]=(f16)b.z; v[7]=(f16)b.w;
                hp2[nb][kb] = v;
            }
        }

        // ---- layer 1: hp = relu(x Wn0^T + bn0) ----
#pragma unroll
        for (int ft = 0; ft < 4; ++ft) {
            const f16x8 w0 = wfrag(0, ft, 0), w1 = wfrag(0, ft, 1);
            const f32x4 bv = bias4(0, ft);
#pragma unroll
            for (int nb = 0; nb < 2; ++nb) {
                f32x4 an = bv;
                an = __builtin_amdgcn_mfma_f32_16x16x32_f16(w0, hp2[nb][0], an, 0, 0, 0);
                an = __builtin_amdgcn_mfma_f32_16x16x32_f16(w1, hp2[nb][1], an, 0, 0, 0);
#pragma unroll
                for (int r = 0; r < 4; ++r)
                    hp[nb][ft >> 1][(ft & 1) * 4 + r] = (f16)fmaxf(an[r], 0.f);
            }
        }

        // ---- layers 2..6 (runtime loop keeps lifetimes per-layer) ----
#pragma unroll 1
        for (int l = 2; l <= 6; ++l) {
            const int pn = l - 1, ps = l + 5;   // 7 + (l-2)
            f16x8 hnew[2][2];
#pragma unroll
            for (int ft = 0; ft < 4; ++ft) {
                const f16x8 wn0 = wfrag(pn, ft, 0), wn1 = wfrag(pn, ft, 1);
                const f16x8 ws0 = wfrag(ps, ft, 0), ws1 = wfrag(ps, ft, 1);
                const f32x4 bnv = bias4(pn, ft),  bsv = bias4(ps, ft);
#pragma unroll
                for (int nb = 0; nb < 2; ++nb) {
                    f32x4 an = bnv, as = bsv;
                    an = __builtin_amdgcn_mfma_f32_16x16x32_f16(wn0, hp[nb][0],  an, 0, 0, 0);
                    an = __builtin_amdgcn_mfma_f32_16x16x32_f16(wn1, hp[nb][1],  an, 0, 0, 0);
                    as = __builtin_amdgcn_mfma_f32_16x16x32_f16(ws0, hp2[nb][0], as, 0, 0, 0);
                    as = __builtin_amdgcn_mfma_f32_16x16x32_f16(ws1, hp2[nb][1], as, 0, 0, 0);
#pragma unroll
                    for (int r = 0; r < 4; ++r)
                        hnew[nb][ft >> 1][(ft & 1) * 4 + r] =
                            (f16)(fmaxf(an[r], 0.f) + fmaxf(as[r], 0.f));
                }
            }
#pragma unroll
            for (int nb = 0; nb < 2; ++nb)
#pragma unroll
            for (int kb = 0; kb < 2; ++kb) {
                hp2[nb][kb] = hp[nb][kb];
                hp[nb][kb]  = hnew[nb][kb];
            }
        }

        // ---- layer 7: out = relu(h6 Wn6^T + bn6) + relu(h5 Ws5^T + bs5), fp32 store ----
#pragma unroll
        for (int ft = 0; ft < 4; ++ft) {
            const f16x8 wn0 = wfrag(6, ft, 0),  wn1 = wfrag(6, ft, 1);
            const f16x8 ws0 = wfrag(12, ft, 0), ws1 = wfrag(12, ft, 1);
            const f32x4 bnv = bias4(6, ft),     bsv = bias4(12, ft);
#pragma unroll
            for (int nb = 0; nb < 2; ++nb) {
                f32x4 an = bnv, as = bsv;
                an = __builtin_amdgcn_mfma_f32_16x16x32_f16(wn0, hp[nb][0],  an, 0, 0, 0);
                an = __builtin_amdgcn_mfma_f32_16x16x32_f16(wn1, hp[nb][1],  an, 0, 0, 0);
                as = __builtin_amdgcn_mfma_f32_16x16x32_f16(ws0, hp2[nb][0], as, 0, 0, 0);
                as = __builtin_amdgcn_mfma_f32_16x16x32_f16(ws1, hp2[nb][1], as, 0, 0, 0);
                f32x4 v;
#pragma unroll
                for (int r = 0; r < 4; ++r) v[r] = fmaxf(an[r], 0.f) + fmaxf(as[r], 0.f);
                float* orow = out + (row0 + nb * 16 + l15) * 64;
                __builtin_memcpy(orow + ft * 16 + q * 4, &v, 16);
            }
        }
    }
}

extern "C" void kernel_launch(void* const* d_in, const int* in_sizes, int n_in,
                              void* d_out, int out_size, void* d_ws, size_t ws_size,
                              hipStream_t stream) {
    (void)in_sizes; (void)n_in; (void)d_ws; (void)ws_size; (void)out_size;
    const float* x  = (const float*)d_in[0];
    const float* Wn = (const float*)d_in[1];
    const float* bn = (const float*)d_in[2];
    const float* Ws = (const float*)d_in[3];
    const float* bs = (const float*)d_in[4];
    nn_fused<<<dim3(NBLOCKS), dim3(THREADS), 0, stream>>>(x, Wn, bn, Ws, bs, (float*)d_out);
}